// Round 1
// 119.381 us; speedup vs baseline: 1.0103x; 1.0103x over previous
//
#include <hip/hip_runtime.h>

// 22-qubit QAOA state-vector sim. Register/LDS-transpose butterflies,
// fp16-packed state (computed in f32). Butterfly c = cb*c + i*sb*partner is
// symmetric, so each stage runs where the partner lives.
// R6: re-split 13/9 -> 14/8. K2 now covers GRP=64 lo-columns x 256 hi-rows:
// every strided access (st read/write, h read) is a 256B wave segment (was
// 128B), the two SHFL(32) stages vanish (8 hi bits = 4 reg + 4 wave), and
// h/hS are prefetched at kernel entry to hide cold-HBM latency under the
// butterflies. K1/K3 move to TPB=1024 with a clean 4bit-wave<->4bit-reg
// LDS transpose; all global access stays 256B-coalesced.
//   K1: init + phase1 + layer1 bits 0-13   (contiguous)
//   K2: layer1 bits 14-21 + phase2 + layer2 bits 14-21  (256B strided)
//   K3: layer2 bits 0-13 + fused |c|^2*hS reduce -> one atomicAdd per block

#define NTOT    (1u << 22)
#define LO_BITS 14
#define HI_BITS 8
#define LO      (1u << LO_BITS)   // 16384
#define HI      (1u << HI_BITS)   // 256
#define GRP     64                // lo-columns per K2 block (256B segments)
#define TPB     1024
#define R       16                // complex elements per thread

typedef __fp16 h2_t __attribute__((ext_vector_type(2)));
union PkU { unsigned u; h2_t h; };

__device__ __forceinline__ unsigned pk(float x, float y) {
    PkU p; p.h = __builtin_amdgcn_cvt_pkrtz(x, y); return p.u;
}
__device__ __forceinline__ float2 unpk(unsigned v) {
    PkU p; p.u = v; return make_float2((float)p.h.x, (float)p.h.y);
}

// register butterfly on register-index bit MASK (f32)
#define REGSTAGE(MASK, CB, SB) {                                  \
    _Pragma("unroll")                                             \
    for (int r0 = 0; r0 < R; ++r0) {                              \
        if ((r0 & (MASK)) == 0) {                                 \
            const int r1 = r0 | (MASK);                           \
            float t0r = re[r0], t0i = im[r0];                     \
            float t1r = re[r1], t1i = im[r1];                     \
            re[r0] = (CB) * t0r - (SB) * t1i;                     \
            im[r0] = (CB) * t0i + (SB) * t1r;                     \
            re[r1] = (CB) * t1r - (SB) * t0i;                     \
            im[r1] = (CB) * t1i + (SB) * t0r;                     \
        } } }

// cross-lane butterfly: ONE packed-half2 shuffle per element
#define SHFLSTAGE(MASK, CB, SB) {                                 \
    _Pragma("unroll")                                             \
    for (int r = 0; r < R; ++r) {                                 \
        unsigned pv = (unsigned)__shfl_xor((int)pk(re[r], im[r]), (MASK), 64); \
        float2 p = unpk(pv);                                      \
        float tr = re[r], ti = im[r];                             \
        re[r] = (CB) * tr - (SB) * p.y;                           \
        im[r] = (CB) * ti + (SB) * p.x;                           \
    } }

// ---------------- K1: init + phase1 + layer-1 bits 0-13 ----------------
// element j = (r<<10)|(w<<6)|lane : bits0-5=lane, 6-9=wave, 10-13=reg
__global__ __launch_bounds__(TPB, 4) void k_init_low(
    const float* __restrict__ h, const float* __restrict__ gam,
    const float* __restrict__ bet, unsigned* __restrict__ st,
    float* __restrict__ out)
{
    __shared__ unsigned sC[LO];   // 64 KB
    const float g1 = gam[0];
    const float cb = __cosf(bet[0]), sb = __sinf(bet[0]);
    const unsigned t = threadIdx.x, lane = t & 63u, w = t >> 6;   // w: 0..15
    const size_t base = (size_t)blockIdx.x * LO;
    float re[R], im[R];

    if (blockIdx.x == 0 && t == 0) out[0] = 0.f;   // K3 accumulates later

    #pragma unroll
    for (int r = 0; r < R; ++r) {
        float s, c;
        __sincosf(g1 * h[base + ((unsigned)r << 10) + t], &s, &c);
        re[r] = c * 0x1p-11f;
        im[r] = s * 0x1p-11f;
    }
    REGSTAGE(1, cb, sb)  REGSTAGE(2, cb, sb)      // bits 10,11
    REGSTAGE(4, cb, sb)  REGSTAGE(8, cb, sb)      // bits 12,13
    SHFLSTAGE(1,  cb, sb) SHFLSTAGE(2,  cb, sb)   // bits 0,1
    SHFLSTAGE(4,  cb, sb) SHFLSTAGE(8,  cb, sb)   // bits 2,3
    SHFLSTAGE(16, cb, sb) SHFLSTAGE(32, cb, sb)   // bits 4,5
    // transpose: swap wave bits 6-9 <-> reg bits 10-13
    #pragma unroll
    for (int r = 0; r < R; ++r) sC[((unsigned)r << 10) | t] = pk(re[r], im[r]);
    __syncthreads();
    #pragma unroll
    for (int r = 0; r < R; ++r) {
        unsigned j = (w << 10) | ((unsigned)r << 6) | lane;
        float2 v = unpk(sC[j]); re[r] = v.x; im[r] = v.y;
    }
    REGSTAGE(1, cb, sb)  REGSTAGE(2, cb, sb)
    REGSTAGE(4, cb, sb)  REGSTAGE(8, cb, sb)      // bits 6,7,8,9
    #pragma unroll
    for (int r = 0; r < R; ++r) {
        unsigned j = (w << 10) | ((unsigned)r << 6) | lane;
        st[base + j] = pk(re[r], im[r]);
    }
}

// -------- K2: layer-1 bits 14-21 + phase2 + layer-2 bits 14-21 --------
// lane = g (all 6 bits: lo-column -> 256B segments); wave w(4); reg r(4).
// mapping A: hi = w | r<<4   (reg = hi bits 4-7)
// mapping B: hi = r | w<<4   (reg = hi bits 0-3)
__global__ __launch_bounds__(TPB, 4) void k_high(
    const float* __restrict__ h, const float* __restrict__ gam,
    const float* __restrict__ bet, unsigned* __restrict__ st)
{
    __shared__ unsigned sC[GRP * HI];   // 16384 words, 64 KB
    const float g2  = gam[1];
    const float cb1 = __cosf(bet[0]), sb1 = __sinf(bet[0]);
    const float cb2 = __cosf(bet[1]), sb2 = __sinf(bet[1]);
    const unsigned t = threadIdx.x, g = t & 63u, w = t >> 6;  // w: 0..15
    const unsigned lo0 = blockIdx.x * GRP;
    float re[R], im[R], hv[R];

    // load at mapping A: 64 lanes x 4B = 256B segments
    #pragma unroll
    for (int r = 0; r < R; ++r) {
        unsigned hi = w | ((unsigned)r << 4);
        float2 v = unpk(st[(size_t)hi * LO + lo0 + g]);
        re[r] = v.x; im[r] = v.y;
    }
    // prefetch h at mapping B (needed after T1) -- hides HBM latency
    #pragma unroll
    for (int r = 0; r < R; ++r) {
        unsigned hi = (unsigned)r | (w << 4);
        hv[r] = h[(size_t)hi * LO + lo0 + g];
    }
    // layer1: hi bits 4-7 (reg @ A)
    REGSTAGE(1, cb1, sb1)  REGSTAGE(2, cb1, sb1)
    REGSTAGE(4, cb1, sb1)  REGSTAGE(8, cb1, sb1)
    // T1: A -> B  (LDS index = g | hi<<6; 64-consecutive-word accesses)
    #pragma unroll
    for (int r = 0; r < R; ++r)
        sC[g | (w << 6) | ((unsigned)r << 10)] = pk(re[r], im[r]);
    __syncthreads();
    #pragma unroll
    for (int r = 0; r < R; ++r) {
        float2 v = unpk(sC[g | ((unsigned)r << 6) | (w << 10)]);
        re[r] = v.x; im[r] = v.y;
    }
    REGSTAGE(1, cb1, sb1)  REGSTAGE(2, cb1, sb1)
    REGSTAGE(4, cb1, sb1)  REGSTAGE(8, cb1, sb1)   // hi bits 0-3; layer1 done
    // phase2 (prefetched h)
    #pragma unroll
    for (int r = 0; r < R; ++r) {
        float s, c;
        __sincosf(g2 * hv[r], &s, &c);
        float tr = re[r], ti = im[r];
        re[r] = tr * c - ti * s;
        im[r] = tr * s + ti * c;
    }
    // layer2 at B: hi bits 0-3 (reg)
    REGSTAGE(1, cb2, sb2)  REGSTAGE(2, cb2, sb2)
    REGSTAGE(4, cb2, sb2)  REGSTAGE(8, cb2, sb2)
    // T2: B -> A
    __syncthreads();
    #pragma unroll
    for (int r = 0; r < R; ++r)
        sC[g | ((unsigned)r << 6) | (w << 10)] = pk(re[r], im[r]);
    __syncthreads();
    #pragma unroll
    for (int r = 0; r < R; ++r) {
        float2 v = unpk(sC[g | (w << 6) | ((unsigned)r << 10)]);
        re[r] = v.x; im[r] = v.y;
    }
    REGSTAGE(1, cb2, sb2)  REGSTAGE(2, cb2, sb2)
    REGSTAGE(4, cb2, sb2)  REGSTAGE(8, cb2, sb2)   // hi bits 4-7; layer2 done
    // store at mapping A
    #pragma unroll
    for (int r = 0; r < R; ++r) {
        unsigned hi = w | ((unsigned)r << 4);
        st[(size_t)hi * LO + lo0 + g] = pk(re[r], im[r]);
    }
}

// -------- K3: layer-2 bits 0-13 + fused |c|^2 * hS -> atomicAdd --------
__global__ __launch_bounds__(TPB, 4) void k_low2(
    const float* __restrict__ hS, const float* __restrict__ bet,
    const unsigned* __restrict__ st, float* __restrict__ out)
{
    __shared__ unsigned sC[LO];   // 64 KB (reused for wave sums at the end)
    const float cb = __cosf(bet[1]), sb = __sinf(bet[1]);
    const unsigned t = threadIdx.x, lane = t & 63u, w = t >> 6;
    const size_t base = (size_t)blockIdx.x * LO;
    float re[R], im[R], hv[R];

    #pragma unroll
    for (int r = 0; r < R; ++r) {
        float2 v = unpk(st[base + ((unsigned)r << 10) + t]);
        re[r] = v.x; im[r] = v.y;
    }
    // prefetch hS at final (post-transpose) indices -- hides cold-HBM latency
    #pragma unroll
    for (int r = 0; r < R; ++r) {
        unsigned j = (w << 10) | ((unsigned)r << 6) | lane;
        hv[r] = hS[base + j];
    }
    REGSTAGE(1, cb, sb)  REGSTAGE(2, cb, sb)
    REGSTAGE(4, cb, sb)  REGSTAGE(8, cb, sb)       // bits 10-13
    SHFLSTAGE(1,  cb, sb) SHFLSTAGE(2,  cb, sb)
    SHFLSTAGE(4,  cb, sb) SHFLSTAGE(8,  cb, sb)
    SHFLSTAGE(16, cb, sb) SHFLSTAGE(32, cb, sb)    // bits 0-5
    #pragma unroll
    for (int r = 0; r < R; ++r) sC[((unsigned)r << 10) | t] = pk(re[r], im[r]);
    __syncthreads();
    #pragma unroll
    for (int r = 0; r < R; ++r) {
        unsigned j = (w << 10) | ((unsigned)r << 6) | lane;
        float2 v = unpk(sC[j]); re[r] = v.x; im[r] = v.y;
    }
    REGSTAGE(1, cb, sb)  REGSTAGE(2, cb, sb)
    REGSTAGE(4, cb, sb)  REGSTAGE(8, cb, sb)       // bits 6-9
    float acc = 0.f;
    #pragma unroll
    for (int r = 0; r < R; ++r)
        acc = fmaf(re[r] * re[r] + im[r] * im[r], hv[r], acc);
    #pragma unroll
    for (int off = 32; off >= 1; off >>= 1)
        acc += __shfl_down(acc, off, 64);
    __syncthreads();                     // sC reads done; safe to reuse
    if (lane == 0) ((float*)sC)[w] = acc;
    __syncthreads();
    if (t == 0) {
        float s = 0.f;
        #pragma unroll
        for (int ww = 0; ww < TPB / 64; ++ww) s += ((float*)sC)[ww];
        unsafeAtomicAdd(out, s);   // native global_atomic_add_f32
    }
}

extern "C" void kernel_launch(void* const* d_in, const int* in_sizes, int n_in,
                              void* d_out, int out_size, void* d_ws, size_t ws_size,
                              hipStream_t stream)
{
    (void)in_sizes; (void)n_in; (void)out_size; (void)ws_size;
    const float* h   = (const float*)d_in[0];
    const float* hS  = (const float*)d_in[1];
    const float* gam = (const float*)d_in[2];
    const float* bet = (const float*)d_in[3];
    unsigned* st = (unsigned*)d_ws;       // 16 MB half2 state
    float* out   = (float*)d_out;

    k_init_low<<<dim3(NTOT / LO), dim3(TPB), 0, stream>>>(h, gam, bet, st, out);
    k_high    <<<dim3(LO / GRP),  dim3(TPB), 0, stream>>>(h, gam, bet, st);
    k_low2    <<<dim3(NTOT / LO), dim3(TPB), 0, stream>>>(hS, bet, st, out);
}